// Round 12
// baseline (1001.802 us; speedup 1.0000x reference)
//
#include <hip/hip_runtime.h>

// GCN 3-layer, N=100000, E=1600000, D=128. bf16 intermediates, MFMA GEMM.
// Feature dim sliced into 8 x 16-col slices; slice s bound to XCD s via blockIdx&7
// (gather working set per XCD = 3.2MB slice -> fits 4MB per-XCD L2).
// Layouts: g-buffers bufA/bufB are SLICED: buf[s][node][16cols] (ushort).
// CSR build (tile-binned, LDS-staged) unchanged from R7.
// Per layer L:
//   gemm_g:  bufA = bf16( dinv[i] * (f(in) @ W) )  (f fused; Wt in LDS swizzled)
//            epilogue stores sliced; EPI A-frag loads sliced.
//   gather:  bufB[s][i] = bf16( g[s][i] + sum_{e: dst=i} g[s][src] )
//            8 lanes/edge (32B slice-row), 8 edge-slots/wave, shfl_xor reduce,
//            nontemporal ssrc/B to keep L2 for the A slice.
// Final: out[c] = mean_i relu(dinv[i]*bufB[i][c] + b3[c])

typedef short bf16x8 __attribute__((ext_vector_type(8)));
typedef float f32x4 __attribute__((ext_vector_type(4)));

__device__ __forceinline__ ushort f2bf(float f) {
  uint u = __builtin_bit_cast(uint, f);
  return (ushort)((u + 0x7fffu + ((u >> 16) & 1u)) >> 16);
}
__device__ __forceinline__ float bflo(uint u) { return __builtin_bit_cast(float, u << 16); }
__device__ __forceinline__ float bfhi(uint u) { return __builtin_bit_cast(float, u & 0xffff0000u); }
__device__ __forceinline__ uint packbf(float x, float y) {
  uint ux = __builtin_bit_cast(uint, x), uy = __builtin_bit_cast(uint, y);
  uint rx = (ux + 0x7fffu + ((ux >> 16) & 1u)) >> 16;
  uint ry = (uy + 0x7fffu + ((uy >> 16) & 1u)) & 0xffff0000u;
  return rx | ry;
}

#define CHUNK 8192

// ---------------- CSR build (tile-binned) ----------------
__global__ __launch_bounds__(256) void chist_k(const int* __restrict__ ei,
                                               int* __restrict__ cnt, int e, int nb) {
  __shared__ int h[512];
  int t = threadIdx.x;
  for (int i = t; i < nb; i += 256) h[i] = 0;
  __syncthreads();
  int base = blockIdx.x * CHUNK;
  int lim = min(base + CHUNK, e);
  for (int i = base + t; i < lim; i += 256)
    atomicAdd(&h[ei[e + i] >> 8], 1);           // dst at ei[E..2E)
  __syncthreads();
  for (int i = t; i < nb; i += 256) if (h[i]) atomicAdd(&cnt[i], h[i]);
}

// nb <= 512 (n <= 131072). Exclusive scan + cursor copy + off[n]=e.
__global__ __launch_bounds__(512) void cscan_k(const int* __restrict__ cnt,
                                               int* __restrict__ cbase,
                                               int* __restrict__ ccur,
                                               int* __restrict__ off,
                                               int nb, int n, int e) {
  __shared__ int s[512];
  int t = threadIdx.x;
  int v = (t < nb) ? cnt[t] : 0;
  s[t] = v;
  __syncthreads();
  for (int d = 1; d < 512; d <<= 1) {
    int x = (t >= d) ? s[t - d] : 0;
    __syncthreads();
    s[t] += x;
    __syncthreads();
  }
  int excl = s[t] - v;
  if (t < nb) { cbase[t] = excl; ccur[t] = excl; }
  if (t == 0) { cbase[nb] = e; off[n] = e; }
}

__global__ __launch_bounds__(256) void binscatter_k(const int* __restrict__ ei,
                                                    int* __restrict__ ccur,
                                                    uint* __restrict__ bpak,
                                                    int e, int nb) {
  __shared__ int lhist[512], gbase[512], lcur[512];
  int t = threadIdx.x;
  for (int i = t; i < nb; i += 256) lhist[i] = 0;
  __syncthreads();
  int base = blockIdx.x * CHUNK;
  int lim = min(base + CHUNK, e);
  for (int i = base + t; i < lim; i += 256)
    atomicAdd(&lhist[ei[e + i] >> 8], 1);
  __syncthreads();
  for (int i = t; i < nb; i += 256) {
    int c = lhist[i];
    gbase[i] = c ? atomicAdd(&ccur[i], c) : 0;
    lcur[i] = 0;
  }
  __syncthreads();
  for (int i = base + t; i < lim; i += 256) {
    int d = ei[e + i];
    int s = ei[i];
    int bin = d >> 8;
    int slot = atomicAdd(&lcur[bin], 1);
    bpak[gbase[bin] + slot] = (uint)s | ((uint)(d & 255) << 24);
  }
}

// One block per 256-node tile: counting sort by dstLocal; emits ssrc, off, dinv.
__global__ __launch_bounds__(256) void binsort_k(const uint* __restrict__ bpak,
                                                 const int* __restrict__ cbase,
                                                 float* __restrict__ dinv,
                                                 int* __restrict__ off,
                                                 int* __restrict__ ssrc, int n) {
  __shared__ int hist[256], cur[256], sc[256];
  int b = blockIdx.x, t = threadIdx.x;
  int beg = cbase[b], end = cbase[b + 1];
  hist[t] = 0;
  __syncthreads();
  for (int j = beg + t; j < end; j += 256) atomicAdd(&hist[bpak[j] >> 24], 1);
  __syncthreads();
  int cnt = hist[t];
  sc[t] = cnt;
  __syncthreads();
  for (int d = 1; d < 256; d <<= 1) {
    int x = (t >= d) ? sc[t - d] : 0;
    __syncthreads();
    sc[t] += x;
    __syncthreads();
  }
  int excl = sc[t] - cnt;
  cur[t] = excl;
  int node = b * 256 + t;
  if (node < n) {
    dinv[node] = rsqrtf((float)cnt + 1.0f);
    off[node] = beg + excl;
  }
  __syncthreads();
  for (int j = beg + t; j < end; j += 256) {
    uint pak = bpak[j];
    int pos = atomicAdd(&cur[pak >> 24], 1);
    ssrc[beg + pos] = (int)(pak & 0xFFFFFFu);
  }
}

// ---------------- W^T cast (3 matrices, 128x128 each) ----------------
__global__ __launch_bounds__(256) void wtcast_k(const float* __restrict__ W1,
                                                const float* __restrict__ W2,
                                                const float* __restrict__ W3,
                                                ushort* __restrict__ Wt1,
                                                ushort* __restrict__ Wt2,
                                                ushort* __restrict__ Wt3) {
  int b = blockIdx.x;
  const float* W = (b < 64) ? W1 : ((b < 128) ? W2 : W3);
  ushort* Wt = (b < 64) ? Wt1 : ((b < 128) ? Wt2 : Wt3);
  int idx = (b & 63) * 256 + threadIdx.x;   // idx = n*128 + k
  int nn = idx >> 7, kk = idx & 127;
  Wt[idx] = f2bf(W[kk * 128 + nn]);
}

// ---------------- MFMA GEMM: 1 wave = 16 rows x 128 cols, Wt in LDS ----------------
// A-frag (16x16x32 bf16): lane l holds A[row = l&15][k = (l>>4)*8 + j], j=0..7
// B-frag:                 lane l holds B[k = (l>>4)*8 + j][col = l&15]  (from Wt[col][k])
// C/D:                    lane l, reg j -> (row = (l>>4)*4 + j, col = l&15)   [m89]
// LDS: 16B slots, slot' = slot ^ (row & 15) -> column reads 2-way = free.
// EPI=1 input and epilogue output use the SLICED layout buf[s][node][16].
template <int EPI>
__global__ __launch_bounds__(256) void gemm_g(
    const void* __restrict__ inv_, const ushort* __restrict__ Wt,
    const float* __restrict__ dinv, const float* __restrict__ bias,
    ushort* __restrict__ outA, int n)
{
  __shared__ ushort sWt[128 * 128];   // 32 KB
  const int t = threadIdx.x;
  const size_t slst = (size_t)n * 16;   // ushorts per slice

  // cooperative swizzled stage of Wt
  {
    const uint4* W4 = (const uint4*)Wt;
    uint4* S4 = (uint4*)sWt;
    #pragma unroll
    for (int j = 0; j < 8; ++j) {
      int idx = t + j * 256;                 // 0..2047 16B-slots
      int row = idx >> 4, slot = idx & 15;
      S4[(row << 4) | (slot ^ (row & 15))] = W4[idx];
    }
  }
  __syncthreads();   // single barrier; all waves participate before any exit

  const int wid = t >> 6, lane = t & 63;
  const int rbase = blockIdx.x * 64 + wid * 16;
  if (rbase >= n) return;

  const int l16 = lane & 15, kc = lane >> 4, k0 = kc * 8;
  int arow = rbase + l16;
  bool rok = arow < n;
  int arow_c = rok ? arow : (n - 1);

  bf16x8 afr[4];
  if constexpr (EPI) {
    const ushort* in = (const ushort*)inv_;
    float dv = dinv[arow_c];
    #pragma unroll
    for (int kk = 0; kk < 4; ++kk) {
      int sl = kk * 2 + (kc >> 1);           // slice of cols kk*32+k0 .. +7
      uint4 r4 = *(const uint4*)(in + (size_t)sl * slst + (size_t)arow_c * 16 + (kc & 1) * 8);
      float4 bb0 = *(const float4*)(bias + kk * 32 + k0);
      float4 bb1 = *(const float4*)(bias + kk * 32 + k0 + 4);
      uint rr[4] = {r4.x, r4.y, r4.z, r4.w};
      float bb[8] = {bb0.x, bb0.y, bb0.z, bb0.w, bb1.x, bb1.y, bb1.z, bb1.w};
      bf16x8 a;
      #pragma unroll
      for (int q = 0; q < 4; ++q) {
        float lo = fmaxf(fmaf(dv, bflo(rr[q]), bb[2 * q]), 0.f);
        float hi = fmaxf(fmaf(dv, bfhi(rr[q]), bb[2 * q + 1]), 0.f);
        a[2 * q]     = (short)f2bf(lo);
        a[2 * q + 1] = (short)f2bf(hi);
      }
      afr[kk] = rok ? a : (bf16x8)0;
    }
  } else {
    const float4* in4 = (const float4*)inv_;
    #pragma unroll
    for (int kk = 0; kk < 4; ++kk) {
      float4 p0 = in4[(size_t)arow_c * 32 + kk * 8 + kc * 2];
      float4 p1 = in4[(size_t)arow_c * 32 + kk * 8 + kc * 2 + 1];
      float f[8] = {p0.x, p0.y, p0.z, p0.w, p1.x, p1.y, p1.z, p1.w};
      bf16x8 a;
      #pragma unroll
      for (int q = 0; q < 8; ++q) a[q] = (short)f2bf(f[q]);
      afr[kk] = rok ? a : (bf16x8)0;
    }
  }

  f32x4 acc[8];
  #pragma unroll
  for (int nt = 0; nt < 8; ++nt) acc[nt] = (f32x4){0.f, 0.f, 0.f, 0.f};

  #pragma unroll
  for (int kk = 0; kk < 4; ++kk) {
    #pragma unroll
    for (int nt = 0; nt < 8; ++nt) {
      int brow = nt * 16 + l16;
      int bslot = kk * 4 + kc;
      bf16x8 bfr = *(const bf16x8*)(sWt + (((brow << 4) | (bslot ^ (brow & 15))) << 3));
      acc[nt] = __builtin_amdgcn_mfma_f32_16x16x32_bf16(afr[kk], bfr, acc[nt], 0, 0, 0);
    }
  }

  // epilogue: g = dinv[row] * acc -> sliced bf16 store (col nt*16+l16 -> slice nt)
  float dvr[4];
  int rr[4];
  #pragma unroll
  for (int j = 0; j < 4; ++j) {
    rr[j] = rbase + kc * 4 + j;
    dvr[j] = (rr[j] < n) ? dinv[rr[j]] : 0.f;
  }
  #pragma unroll
  for (int nt = 0; nt < 8; ++nt) {
    ushort* outs = outA + (size_t)nt * slst + l16;
    #pragma unroll
    for (int j = 0; j < 4; ++j) {
      if (rr[j] < n)
        outs[(size_t)rr[j] * 16] = f2bf(acc[nt][j] * dvr[j]);
    }
  }
}

// ---------------- gather: sliced, XCD-local ----------------
// blockIdx&7 = slice s (round-robin -> XCD s); block = 4 waves = 4 nodes.
// Wave: 8 edge-slots x 8 lanes (one uint each of the 32B slice-row).
// shfl_xor butterfly over slot bits; slot 0 adds self term and writes.
__global__ __launch_bounds__(256) void gather_k(const uint* __restrict__ A,
                                                uint* __restrict__ B,
                                                const int* __restrict__ ssrc,
                                                const int* __restrict__ off, int n) {
  int s = blockIdx.x & 7;
  int w = (blockIdx.x >> 3) * 4 + (threadIdx.x >> 6);
  if (w >= n) return;
  int lane = threadIdx.x & 63;
  int slot = lane >> 3, cu = lane & 7;
  const uint* As = A + (size_t)s * n * 8;
  int beg = off[w], end = off[w + 1];
  float ax = 0.f, ay = 0.f;
  int j = beg + slot;
  for (; j + 8 < end; j += 16) {   // 2 independent chains per slot
    int s0 = __builtin_nontemporal_load(&ssrc[j]);
    int s1 = __builtin_nontemporal_load(&ssrc[j + 8]);
    uint v0 = As[(size_t)s0 * 8 + cu];
    uint v1 = As[(size_t)s1 * 8 + cu];
    ax += bflo(v0) + bflo(v1);
    ay += bfhi(v0) + bfhi(v1);
  }
  if (j < end) {
    int s0 = __builtin_nontemporal_load(&ssrc[j]);
    uint v0 = As[(size_t)s0 * 8 + cu];
    ax += bflo(v0); ay += bfhi(v0);
  }
  ax += __shfl_xor(ax, 8, 64);  ay += __shfl_xor(ay, 8, 64);
  ax += __shfl_xor(ax, 16, 64); ay += __shfl_xor(ay, 16, 64);
  ax += __shfl_xor(ax, 32, 64); ay += __shfl_xor(ay, 32, 64);
  if (slot == 0) {
    uint sv = As[(size_t)w * 8 + cu];          // self-loop term g[i]
    ax += bflo(sv); ay += bfhi(sv);
    __builtin_nontemporal_store(packbf(ax, ay), &B[(size_t)s * n * 8 + (size_t)w * 8 + cu]);
  }
}

// ---------------- mean: partials then reduce (sliced input) ----------------
__global__ __launch_bounds__(256) void mean1_k(const uint* __restrict__ B,
                                               const float* __restrict__ dinv,
                                               const float* __restrict__ bias,
                                               float* __restrict__ part, int n) {
  __shared__ float s[512];
  int t = threadIdx.x, cg = t & 63, rg = t >> 6;
  const uint* Bs = B + (size_t)(cg >> 3) * n * 8 + (cg & 7);
  float bx = bias[cg * 2], by = bias[cg * 2 + 1];
  float sx = 0.f, sy = 0.f;
  for (int row = blockIdx.x * 4 + rg; row < n; row += 1024) {
    uint v = Bs[(size_t)row * 8];
    float dv = dinv[row];
    sx += fmaxf(fmaf(dv, bflo(v), bx), 0.f);
    sy += fmaxf(fmaf(dv, bfhi(v), by), 0.f);
  }
  s[t * 2] = sx; s[t * 2 + 1] = sy;
  __syncthreads();
  if (t < 64) {
    float rx = s[t * 2] + s[(t + 64) * 2] + s[(t + 128) * 2] + s[(t + 192) * 2];
    float ry = s[t * 2 + 1] + s[(t + 64) * 2 + 1] + s[(t + 128) * 2 + 1] + s[(t + 192) * 2 + 1];
    part[blockIdx.x * 128 + cg * 2] = rx;
    part[blockIdx.x * 128 + cg * 2 + 1] = ry;
  }
}

__global__ __launch_bounds__(128) void mean2_k(const float* __restrict__ part,
                                               float* __restrict__ out, float invn) {
  int c = threadIdx.x;
  float s = 0.f;
  for (int b = 0; b < 256; ++b) s += part[b * 128 + c];
  out[c] = s * invn;
}

extern "C" void kernel_launch(void* const* d_in, const int* in_sizes, int n_in,
                              void* d_out, int out_size, void* d_ws, size_t ws_size,
                              hipStream_t stream) {
  const float* x  = (const float*)d_in[0];
  const int*   ei = (const int*)d_in[1];
  const float* W1 = (const float*)d_in[2];
  const float* b1 = (const float*)d_in[3];
  const float* W2 = (const float*)d_in[4];
  const float* b2 = (const float*)d_in[5];
  const float* W3 = (const float*)d_in[6];
  const float* b3 = (const float*)d_in[7];
  float* out = (float*)d_out;

  const int n = in_sizes[0] / 128;
  const int e = in_sizes[1] / 2;
  const int nb = (n + 255) / 256;          // 256-node tiles (nb <= 512)
  const int nchunk = (e + CHUNK - 1) / CHUNK;

  char* p = (char*)d_ws;
  auto alloc = [&](size_t bytes) {
    char* r = p;
    p += (bytes + 255) & ~(size_t)255;
    return r;
  };
  int*    cnt   = (int*)alloc((size_t)nb * 4);
  int*    cbase = (int*)alloc((size_t)(nb + 1) * 4);
  int*    ccur  = (int*)alloc((size_t)nb * 4);
  int*    off   = (int*)alloc((size_t)(n + 1) * 4);
  float*  dinv  = (float*)alloc((size_t)n * 4);
  uint*   bpak  = (uint*)alloc((size_t)e * 4);
  int*    ssrc  = (int*)alloc((size_t)e * 4);
  ushort* Wt1   = (ushort*)alloc(128 * 128 * 2);
  ushort* Wt2   = (ushort*)alloc(128 * 128 * 2);
  ushort* Wt3   = (ushort*)alloc(128 * 128 * 2);
  ushort* bufA  = (ushort*)alloc((size_t)n * 128 * 2);
  ushort* bufB  = (ushort*)alloc((size_t)n * 128 * 2);
  float*  part  = (float*)alloc(256 * 128 * 4);

  // CSR build (tile-binned) + dinv + Wt
  hipMemsetAsync(cnt, 0, (size_t)nb * 4, stream);
  chist_k     <<<nchunk, 256, 0, stream>>>(ei, cnt, e, nb);
  cscan_k     <<<1, 512, 0, stream>>>(cnt, cbase, ccur, off, nb, n, e);
  binscatter_k<<<nchunk, 256, 0, stream>>>(ei, ccur, bpak, e, nb);
  binsort_k   <<<nb, 256, 0, stream>>>(bpak, cbase, dinv, off, ssrc, n);
  wtcast_k    <<<192, 256, 0, stream>>>(W1, W2, W3, Wt1, Wt2, Wt3);

  const int gb = (n + 63) / 64;
  const int ab = ((n + 3) / 4) * 8;        // 4 nodes/block x 8 slices; bid&7 = slice

  gemm_g<0><<<gb, 256, 0, stream>>>(x, Wt1, dinv, nullptr, bufA, n);
  gather_k <<<ab, 256, 0, stream>>>((const uint*)bufA, (uint*)bufB, ssrc, off, n);
  gemm_g<1><<<gb, 256, 0, stream>>>(bufB, Wt2, dinv, b1, bufA, n);
  gather_k <<<ab, 256, 0, stream>>>((const uint*)bufA, (uint*)bufB, ssrc, off, n);
  gemm_g<1><<<gb, 256, 0, stream>>>(bufB, Wt3, dinv, b2, bufA, n);
  gather_k <<<ab, 256, 0, stream>>>((const uint*)bufA, (uint*)bufB, ssrc, off, n);

  mean1_k<<<256, 256, 0, stream>>>((const uint*)bufB, dinv, b3, part, n);
  mean2_k<<<1, 128, 0, stream>>>(part, out, 1.0f / (float)n);
}

// Round 13
// 446.857 us; speedup vs baseline: 2.2419x; 2.2419x over previous
//
#include <hip/hip_runtime.h>

// GCN 3-layer, N=100000, E=1600000, D=128. bf16 intermediates, MFMA GEMM.
// (R11 structure restored; R12's sliced-gather experiment regressed 2.3x:
//  scattered 32B segments multiplied memory-system requests. Keep coalesced
//  256B row gathers + deep MLP.)
// CSR build (tile-binned, LDS-staged; 256-node tiles):
//   chist_k -> cscan_k -> binscatter_k (bpak = src|dstLocal<<24) -> binsort_k
// Per layer L:
//   gemm_g:  bufA = bf16( dinv[i] * (f(in) @ W) )  (f fused; Wt in LDS swizzled)
//   gather:  bufB[i] = bf16( g[i] + sum_{e: dst=i} g[src] )  (16-deep pipeline,
//            nontemporal ssrc so L2 keeps g-rows)
// Final: out[c] = mean_i relu(dinv[i]*bufB[i][c] + b3[c])

typedef short bf16x8 __attribute__((ext_vector_type(8)));
typedef float f32x4 __attribute__((ext_vector_type(4)));

__device__ __forceinline__ ushort f2bf(float f) {
  uint u = __builtin_bit_cast(uint, f);
  return (ushort)((u + 0x7fffu + ((u >> 16) & 1u)) >> 16);
}
__device__ __forceinline__ float bflo(uint u) { return __builtin_bit_cast(float, u << 16); }
__device__ __forceinline__ float bfhi(uint u) { return __builtin_bit_cast(float, u & 0xffff0000u); }
__device__ __forceinline__ uint packbf(float x, float y) {
  uint ux = __builtin_bit_cast(uint, x), uy = __builtin_bit_cast(uint, y);
  uint rx = (ux + 0x7fffu + ((ux >> 16) & 1u)) >> 16;
  uint ry = (uy + 0x7fffu + ((uy >> 16) & 1u)) & 0xffff0000u;
  return rx | ry;
}

#define CHUNK 8192

// ---------------- CSR build (tile-binned) ----------------
__global__ __launch_bounds__(256) void chist_k(const int* __restrict__ ei,
                                               int* __restrict__ cnt, int e, int nb) {
  __shared__ int h[512];
  int t = threadIdx.x;
  for (int i = t; i < nb; i += 256) h[i] = 0;
  __syncthreads();
  int base = blockIdx.x * CHUNK;
  int lim = min(base + CHUNK, e);
  for (int i = base + t; i < lim; i += 256)
    atomicAdd(&h[ei[e + i] >> 8], 1);           // dst at ei[E..2E)
  __syncthreads();
  for (int i = t; i < nb; i += 256) if (h[i]) atomicAdd(&cnt[i], h[i]);
}

// nb <= 512 (n <= 131072). Exclusive scan + cursor copy + off[n]=e.
__global__ __launch_bounds__(512) void cscan_k(const int* __restrict__ cnt,
                                               int* __restrict__ cbase,
                                               int* __restrict__ ccur,
                                               int* __restrict__ off,
                                               int nb, int n, int e) {
  __shared__ int s[512];
  int t = threadIdx.x;
  int v = (t < nb) ? cnt[t] : 0;
  s[t] = v;
  __syncthreads();
  for (int d = 1; d < 512; d <<= 1) {
    int x = (t >= d) ? s[t - d] : 0;
    __syncthreads();
    s[t] += x;
    __syncthreads();
  }
  int excl = s[t] - v;
  if (t < nb) { cbase[t] = excl; ccur[t] = excl; }
  if (t == 0) { cbase[nb] = e; off[n] = e; }
}

__global__ __launch_bounds__(256) void binscatter_k(const int* __restrict__ ei,
                                                    int* __restrict__ ccur,
                                                    uint* __restrict__ bpak,
                                                    int e, int nb) {
  __shared__ int lhist[512], gbase[512], lcur[512];
  int t = threadIdx.x;
  for (int i = t; i < nb; i += 256) lhist[i] = 0;
  __syncthreads();
  int base = blockIdx.x * CHUNK;
  int lim = min(base + CHUNK, e);
  for (int i = base + t; i < lim; i += 256)
    atomicAdd(&lhist[ei[e + i] >> 8], 1);
  __syncthreads();
  for (int i = t; i < nb; i += 256) {
    int c = lhist[i];
    gbase[i] = c ? atomicAdd(&ccur[i], c) : 0;
    lcur[i] = 0;
  }
  __syncthreads();
  for (int i = base + t; i < lim; i += 256) {
    int d = ei[e + i];
    int s = ei[i];
    int bin = d >> 8;
    int slot = atomicAdd(&lcur[bin], 1);
    bpak[gbase[bin] + slot] = (uint)s | ((uint)(d & 255) << 24);
  }
}

// One block per 256-node tile: counting sort by dstLocal; emits ssrc, off, dinv.
__global__ __launch_bounds__(256) void binsort_k(const uint* __restrict__ bpak,
                                                 const int* __restrict__ cbase,
                                                 float* __restrict__ dinv,
                                                 int* __restrict__ off,
                                                 int* __restrict__ ssrc, int n) {
  __shared__ int hist[256], cur[256], sc[256];
  int b = blockIdx.x, t = threadIdx.x;
  int beg = cbase[b], end = cbase[b + 1];
  hist[t] = 0;
  __syncthreads();
  for (int j = beg + t; j < end; j += 256) atomicAdd(&hist[bpak[j] >> 24], 1);
  __syncthreads();
  int cnt = hist[t];
  sc[t] = cnt;
  __syncthreads();
  for (int d = 1; d < 256; d <<= 1) {
    int x = (t >= d) ? sc[t - d] : 0;
    __syncthreads();
    sc[t] += x;
    __syncthreads();
  }
  int excl = sc[t] - cnt;
  cur[t] = excl;
  int node = b * 256 + t;
  if (node < n) {
    dinv[node] = rsqrtf((float)cnt + 1.0f);
    off[node] = beg + excl;
  }
  __syncthreads();
  for (int j = beg + t; j < end; j += 256) {
    uint pak = bpak[j];
    int pos = atomicAdd(&cur[pak >> 24], 1);
    ssrc[beg + pos] = (int)(pak & 0xFFFFFFu);
  }
}

// ---------------- W^T cast (3 matrices, 128x128 each) ----------------
__global__ __launch_bounds__(256) void wtcast_k(const float* __restrict__ W1,
                                                const float* __restrict__ W2,
                                                const float* __restrict__ W3,
                                                ushort* __restrict__ Wt1,
                                                ushort* __restrict__ Wt2,
                                                ushort* __restrict__ Wt3) {
  int b = blockIdx.x;
  const float* W = (b < 64) ? W1 : ((b < 128) ? W2 : W3);
  ushort* Wt = (b < 64) ? Wt1 : ((b < 128) ? Wt2 : Wt3);
  int idx = (b & 63) * 256 + threadIdx.x;   // idx = n*128 + k
  int nn = idx >> 7, kk = idx & 127;
  Wt[idx] = f2bf(W[kk * 128 + nn]);
}

// ---------------- MFMA GEMM: 1 wave = 16 rows x 128 cols, Wt in LDS ----------------
// A-frag (16x16x32 bf16): lane l holds A[row = l&15][k = (l>>4)*8 + j], j=0..7
// B-frag:                 lane l holds B[k = (l>>4)*8 + j][col = l&15]  (from Wt[col][k])
// C/D:                    lane l, reg j -> (row = (l>>4)*4 + j, col = l&15)   [m89]
// LDS layout: 16B slots, slot' = slot ^ (row & 15)  -> column reads are 2-way = free.
template <int EPI>
__global__ __launch_bounds__(256) void gemm_g(
    const void* __restrict__ inv_, const ushort* __restrict__ Wt,
    const float* __restrict__ dinv, const float* __restrict__ bias,
    ushort* __restrict__ outA, int n)
{
  __shared__ ushort sWt[128 * 128];   // 32 KB
  const int t = threadIdx.x;

  // cooperative swizzled stage of Wt
  {
    const uint4* W4 = (const uint4*)Wt;
    uint4* S4 = (uint4*)sWt;
    #pragma unroll
    for (int j = 0; j < 8; ++j) {
      int idx = t + j * 256;                 // 0..2047 16B-slots
      int row = idx >> 4, slot = idx & 15;
      S4[(row << 4) | (slot ^ (row & 15))] = W4[idx];
    }
  }
  __syncthreads();   // single barrier; all waves participate before any exit

  const int wid = t >> 6, lane = t & 63;
  const int rbase = blockIdx.x * 64 + wid * 16;
  if (rbase >= n) return;

  const int l16 = lane & 15, kc = lane >> 4, k0 = kc * 8;
  int arow = rbase + l16;
  bool rok = arow < n;
  int arow_c = rok ? arow : (n - 1);

  bf16x8 afr[4];
  if constexpr (EPI) {
    const ushort* in = (const ushort*)inv_;
    float dv = dinv[arow_c];
    #pragma unroll
    for (int kk = 0; kk < 4; ++kk) {
      uint4 r4 = *(const uint4*)(in + (size_t)arow_c * 128 + kk * 32 + k0);
      float4 bb0 = *(const float4*)(bias + kk * 32 + k0);
      float4 bb1 = *(const float4*)(bias + kk * 32 + k0 + 4);
      uint rr[4] = {r4.x, r4.y, r4.z, r4.w};
      float bb[8] = {bb0.x, bb0.y, bb0.z, bb0.w, bb1.x, bb1.y, bb1.z, bb1.w};
      bf16x8 a;
      #pragma unroll
      for (int q = 0; q < 4; ++q) {
        float lo = fmaxf(fmaf(dv, bflo(rr[q]), bb[2 * q]), 0.f);
        float hi = fmaxf(fmaf(dv, bfhi(rr[q]), bb[2 * q + 1]), 0.f);
        a[2 * q]     = (short)f2bf(lo);
        a[2 * q + 1] = (short)f2bf(hi);
      }
      afr[kk] = rok ? a : (bf16x8)0;
    }
  } else {
    const float4* in4 = (const float4*)inv_;
    #pragma unroll
    for (int kk = 0; kk < 4; ++kk) {
      float4 p0 = in4[(size_t)arow_c * 32 + kk * 8 + kc * 2];
      float4 p1 = in4[(size_t)arow_c * 32 + kk * 8 + kc * 2 + 1];
      float f[8] = {p0.x, p0.y, p0.z, p0.w, p1.x, p1.y, p1.z, p1.w};
      bf16x8 a;
      #pragma unroll
      for (int q = 0; q < 8; ++q) a[q] = (short)f2bf(f[q]);
      afr[kk] = rok ? a : (bf16x8)0;
    }
  }

  f32x4 acc[8];
  #pragma unroll
  for (int nt = 0; nt < 8; ++nt) acc[nt] = (f32x4){0.f, 0.f, 0.f, 0.f};

  #pragma unroll
  for (int kk = 0; kk < 4; ++kk) {
    #pragma unroll
    for (int nt = 0; nt < 8; ++nt) {
      int brow = nt * 16 + l16;
      int bslot = kk * 4 + kc;
      bf16x8 bfr = *(const bf16x8*)(sWt + (((brow << 4) | (bslot ^ (brow & 15))) << 3));
      acc[nt] = __builtin_amdgcn_mfma_f32_16x16x32_bf16(afr[kk], bfr, acc[nt], 0, 0, 0);
    }
  }

  // epilogue: g = dinv[row] * acc -> bf16 store
  float dvr[4];
  int rr[4];
  #pragma unroll
  for (int j = 0; j < 4; ++j) {
    rr[j] = rbase + kc * 4 + j;
    dvr[j] = (rr[j] < n) ? dinv[rr[j]] : 0.f;
  }
  #pragma unroll
  for (int nt = 0; nt < 8; ++nt) {
    int col = nt * 16 + l16;
    #pragma unroll
    for (int j = 0; j < 4; ++j) {
      if (rr[j] < n)
        outA[(size_t)rr[j] * 128 + col] = f2bf(acc[nt][j] * dvr[j]);
    }
  }
}

// ---------------- gather: 1 wave per dst node, bf16 rows, 16-deep pipeline ----------------
__global__ __launch_bounds__(256) void gather_k(const uint* __restrict__ A,
                                                uint* __restrict__ B,
                                                const int* __restrict__ ssrc,
                                                const int* __restrict__ off, int n) {
  int w = (blockIdx.x * 256 + threadIdx.x) >> 6;
  int lane = threadIdx.x & 63;
  if (w >= n) return;
  int beg = off[w], end = off[w + 1];
  uint sv = A[(size_t)w * 64 + lane];        // self-loop term g[i]
  float ax = bflo(sv), ay = bfhi(sv);
  int j = beg;
  for (; j + 16 <= end; j += 16) {
    uint v[16];
    #pragma unroll
    for (int q = 0; q < 16; ++q) {
      int s = __builtin_nontemporal_load(&ssrc[j + q]);
      v[q] = A[(size_t)s * 64 + lane];
    }
    #pragma unroll
    for (int q = 0; q < 16; ++q) { ax += bflo(v[q]); ay += bfhi(v[q]); }
  }
  for (; j + 8 <= end; j += 8) {
    uint v[8];
    #pragma unroll
    for (int q = 0; q < 8; ++q) {
      int s = __builtin_nontemporal_load(&ssrc[j + q]);
      v[q] = A[(size_t)s * 64 + lane];
    }
    #pragma unroll
    for (int q = 0; q < 8; ++q) { ax += bflo(v[q]); ay += bfhi(v[q]); }
  }
  for (; j + 4 <= end; j += 4) {
    uint v[4];
    #pragma unroll
    for (int q = 0; q < 4; ++q) {
      int s = __builtin_nontemporal_load(&ssrc[j + q]);
      v[q] = A[(size_t)s * 64 + lane];
    }
    #pragma unroll
    for (int q = 0; q < 4; ++q) { ax += bflo(v[q]); ay += bfhi(v[q]); }
  }
  for (; j < end; ++j) {
    int s = __builtin_nontemporal_load(&ssrc[j]);
    uint v = A[(size_t)s * 64 + lane];
    ax += bflo(v); ay += bfhi(v);
  }
  B[(size_t)w * 64 + lane] = packbf(ax, ay);
}

// ---------------- mean: partials then reduce ----------------
__global__ __launch_bounds__(256) void mean1_k(const uint* __restrict__ B,
                                               const float* __restrict__ dinv,
                                               const float* __restrict__ bias,
                                               float* __restrict__ part, int n) {
  __shared__ float s[512];
  int t = threadIdx.x, cg = t & 63, rg = t >> 6;
  float bx = bias[cg * 2], by = bias[cg * 2 + 1];
  float sx = 0.f, sy = 0.f;
  for (int row = blockIdx.x * 4 + rg; row < n; row += 1024) {
    uint v = B[(size_t)row * 64 + cg];
    float dv = dinv[row];
    sx += fmaxf(fmaf(dv, bflo(v), bx), 0.f);
    sy += fmaxf(fmaf(dv, bfhi(v), by), 0.f);
  }
  s[t * 2] = sx; s[t * 2 + 1] = sy;
  __syncthreads();
  if (t < 64) {
    float rx = s[t * 2] + s[(t + 64) * 2] + s[(t + 128) * 2] + s[(t + 192) * 2];
    float ry = s[t * 2 + 1] + s[(t + 64) * 2 + 1] + s[(t + 128) * 2 + 1] + s[(t + 192) * 2 + 1];
    part[blockIdx.x * 128 + cg * 2] = rx;
    part[blockIdx.x * 128 + cg * 2 + 1] = ry;
  }
}

__global__ __launch_bounds__(128) void mean2_k(const float* __restrict__ part,
                                               float* __restrict__ out, float invn) {
  int c = threadIdx.x;
  float s = 0.f;
  for (int b = 0; b < 256; ++b) s += part[b * 128 + c];
  out[c] = s * invn;
}

extern "C" void kernel_launch(void* const* d_in, const int* in_sizes, int n_in,
                              void* d_out, int out_size, void* d_ws, size_t ws_size,
                              hipStream_t stream) {
  const float* x  = (const float*)d_in[0];
  const int*   ei = (const int*)d_in[1];
  const float* W1 = (const float*)d_in[2];
  const float* b1 = (const float*)d_in[3];
  const float* W2 = (const float*)d_in[4];
  const float* b2 = (const float*)d_in[5];
  const float* W3 = (const float*)d_in[6];
  const float* b3 = (const float*)d_in[7];
  float* out = (float*)d_out;

  const int n = in_sizes[0] / 128;
  const int e = in_sizes[1] / 2;
  const int nb = (n + 255) / 256;          // 256-node tiles (nb <= 512)
  const int nchunk = (e + CHUNK - 1) / CHUNK;

  char* p = (char*)d_ws;
  auto alloc = [&](size_t bytes) {
    char* r = p;
    p += (bytes + 255) & ~(size_t)255;
    return r;
  };
  int*    cnt   = (int*)alloc((size_t)nb * 4);
  int*    cbase = (int*)alloc((size_t)(nb + 1) * 4);
  int*    ccur  = (int*)alloc((size_t)nb * 4);
  int*    off   = (int*)alloc((size_t)(n + 1) * 4);
  float*  dinv  = (float*)alloc((size_t)n * 4);
  uint*   bpak  = (uint*)alloc((size_t)e * 4);
  int*    ssrc  = (int*)alloc((size_t)e * 4);
  ushort* Wt1   = (ushort*)alloc(128 * 128 * 2);
  ushort* Wt2   = (ushort*)alloc(128 * 128 * 2);
  ushort* Wt3   = (ushort*)alloc(128 * 128 * 2);
  ushort* bufA  = (ushort*)alloc((size_t)n * 128 * 2);
  ushort* bufB  = (ushort*)alloc((size_t)n * 128 * 2);
  float*  part  = (float*)alloc(256 * 128 * 4);

  // CSR build (tile-binned) + dinv + Wt
  hipMemsetAsync(cnt, 0, (size_t)nb * 4, stream);
  chist_k     <<<nchunk, 256, 0, stream>>>(ei, cnt, e, nb);
  cscan_k     <<<1, 512, 0, stream>>>(cnt, cbase, ccur, off, nb, n, e);
  binscatter_k<<<nchunk, 256, 0, stream>>>(ei, ccur, bpak, e, nb);
  binsort_k   <<<nb, 256, 0, stream>>>(bpak, cbase, dinv, off, ssrc, n);
  wtcast_k    <<<192, 256, 0, stream>>>(W1, W2, W3, Wt1, Wt2, Wt3);

  const int gb = (n + 63) / 64;
  const int ab = (n * 64 + 255) / 256;     // 1 wave per node

  gemm_g<0><<<gb, 256, 0, stream>>>(x, Wt1, dinv, nullptr, bufA, n);
  gather_k <<<ab, 256, 0, stream>>>((const uint*)bufA, (uint*)bufB, ssrc, off, n);
  gemm_g<1><<<gb, 256, 0, stream>>>(bufB, Wt2, dinv, b1, bufA, n);
  gather_k <<<ab, 256, 0, stream>>>((const uint*)bufA, (uint*)bufB, ssrc, off, n);
  gemm_g<1><<<gb, 256, 0, stream>>>(bufB, Wt3, dinv, b2, bufA, n);
  gather_k <<<ab, 256, 0, stream>>>((const uint*)bufA, (uint*)bufB, ssrc, off, n);

  mean1_k<<<256, 256, 0, stream>>>((const uint*)bufB, dinv, b3, part, n);
  mean2_k<<<1, 128, 0, stream>>>(part, out, 1.0f / (float)n);
}